// Round 20
// baseline (337.448 us; speedup 1.0000x reference)
//
#include <hip/hip_runtime.h>
#include <math.h>

static constexpr int kH  = 80;
static constexpr int kW  = 120;
static constexpr int kHW = kH * kW;     // 9600
static constexpr int kBV = 6;
static constexpr int kD  = 20;

typedef __attribute__((ext_vector_type(8)))  short bf16x8;
typedef __attribute__((ext_vector_type(16))) float f32x16;
typedef __attribute__((ext_vector_type(4)))  int   i32x4;
typedef __attribute__((ext_vector_type(2)))  int   i32x2;
typedef __attribute__((ext_vector_type(4)))  float float4v;

__device__ __forceinline__ float bf16r(float x) {
  unsigned u = __float_as_uint(x);
  u += 0x7FFFu + ((u >> 16) & 1u);
  return __uint_as_float(u & 0xFFFF0000u);
}
__device__ __forceinline__ unsigned short bf16c(float x) {
  unsigned u = __float_as_uint(x);
  u += 0x7FFFu + ((u >> 16) & 1u);
  return (unsigned short)(u >> 16);
}
__device__ __forceinline__ int pack2(float a, float b) {
  return (int)((unsigned)bf16c(a) | ((unsigned)bf16c(b) << 16));
}
__device__ __forceinline__ float bl(unsigned pk) {  // low bf16 of pair -> f32
  return __uint_as_float(pk << 16);
}
__device__ __forceinline__ float bh(unsigned pk) {  // high bf16 of pair -> f32
  return __uint_as_float(pk & 0xFFFF0000u);
}

struct ConstBuf {
  float bn1_s[67], bn1_o[67];
  float bn2_s[64], bn2_o[64];
  float bnf_s[128], bnf_o[128];
  float Kinv[6][9];
  float Rw[6][9];
  float tw[6][3];
  float Kinvc[6][9];
  float intrc[6][9];
  float poseR[2][6][9];
  float poseT[2][6][3];
  float dvals[20];
};

__device__ void inv3x3(const float* A, float* o) {
  float a = A[0], b = A[1], c = A[2];
  float d = A[3], e = A[4], f = A[5];
  float g = A[6], h = A[7], i = A[8];
  float det = a * (e * i - f * h) - b * (d * i - f * g) + c * (d * h - e * g);
  float id = 1.0f / det;
  o[0] = (e * i - f * h) * id;
  o[1] = -(b * i - c * h) * id;
  o[2] = (b * f - c * e) * id;
  o[3] = -(d * i - f * g) * id;
  o[4] = (a * i - c * g) * id;
  o[5] = -(a * f - c * d) * id;
  o[6] = (d * h - e * g) * id;
  o[7] = -(a * h - b * g) * id;
  o[8] = (a * e - b * d) * id;
}

__device__ void inv4x4(const float* A, float* out) {
  float M[4][8];
  for (int r = 0; r < 4; ++r) {
    for (int c = 0; c < 4; ++c) M[r][c] = A[r * 4 + c];
    for (int c = 0; c < 4; ++c) M[r][4 + c] = (r == c) ? 1.0f : 0.0f;
  }
  for (int col = 0; col < 4; ++col) {
    int p = col;
    float best = fabsf(M[col][col]);
    for (int r = col + 1; r < 4; ++r) {
      float v = fabsf(M[r][col]);
      if (v > best) { best = v; p = r; }
    }
    if (p != col)
      for (int c = 0; c < 8; ++c) { float t = M[col][c]; M[col][c] = M[p][c]; M[p][c] = t; }
    float inv = 1.0f / M[col][col];
    for (int c = 0; c < 8; ++c) M[col][c] *= inv;
    for (int r = 0; r < 4; ++r) {
      if (r == col) continue;
      float f = M[r][col];
      for (int c = 0; c < 8; ++c) M[r][c] -= f * M[col][c];
    }
  }
  for (int r = 0; r < 4; ++r)
    for (int c = 0; c < 4; ++c) out[r * 4 + c] = M[r][4 + c];
}

__device__ void mm4(const float* A, const float* B, float* C) {
  for (int r = 0; r < 4; ++r)
    for (int c = 0; c < 4; ++c) {
      float s = 0.0f;
      for (int k = 0; k < 4; ++k) s += A[r * 4 + k] * B[k * 4 + c];
      C[r * 4 + c] = s;
    }
}

// ---------------------------------------------------------------------------
// Kernel 0: constants
// ---------------------------------------------------------------------------
__global__ void consts_kernel(const float* __restrict__ intr, const float* __restrict__ c2,
                              const float* g1, const float* b1, const float* m1, const float* v1,
                              const float* g2, const float* b2, const float* m2, const float* v2,
                              const float* gf, const float* bff, const float* mf, const float* vff,
                              ConstBuf* cb) {
  int tid = threadIdx.x;
  for (int c = tid; c < 67; c += 64) {
    float s = g1[c] / sqrtf(v1[c] + 1e-5f);
    cb->bn1_s[c] = s; cb->bn1_o[c] = b1[c] - m1[c] * s;
  }
  for (int c = tid; c < 64; c += 64) {
    float s = g2[c] / sqrtf(v2[c] + 1e-5f);
    cb->bn2_s[c] = s; cb->bn2_o[c] = b2[c] - m2[c] * s;
  }
  for (int c = tid; c < 128; c += 64) {
    float s = gf[c] / sqrtf(vff[c] + 1e-5f);
    cb->bnf_s[c] = s; cb->bnf_o[c] = bff[c] - mf[c] * s;
  }
  if (tid < 20) {
    float l = (1.0f / 19.0f) * (float)tid;
    cb->dvals[tid] = bf16r(1.0f / (0.01f + l * 9.99f));
  }
  __shared__ float Einv_s[6][16];
  if (tid < 6) {
    float Ki[9];
    inv3x3(intr + tid * 9, Ki);
    for (int k = 0; k < 9; ++k) cb->Kinv[tid][k] = bf16r(Ki[k]);
    const float* T = c2 + tid * 16;
    cb->Rw[tid][0] = bf16r(T[0]);  cb->Rw[tid][1] = bf16r(T[1]);  cb->Rw[tid][2] = bf16r(T[2]);
    cb->Rw[tid][3] = bf16r(T[4]);  cb->Rw[tid][4] = bf16r(T[5]);  cb->Rw[tid][5] = bf16r(T[6]);
    cb->Rw[tid][6] = bf16r(T[8]);  cb->Rw[tid][7] = bf16r(T[9]);  cb->Rw[tid][8] = bf16r(T[10]);
    cb->tw[tid][0] = bf16r(T[3]);  cb->tw[tid][1] = bf16r(T[7]);  cb->tw[tid][2] = bf16r(T[11]);
    inv4x4(T, Einv_s[tid]);
    int vj = tid >> 1, bj = tid & 1, ii = bj * 3 + vj;
    const float* Kk = intr + ii * 9;
    float S[9] = {Kk[0] * 120.0f, Kk[1] * 120.0f, Kk[2] * 120.0f,
                  Kk[3] * 80.0f,  Kk[4] * 80.0f,  Kk[5] * 80.0f,
                  Kk[6],          Kk[7],          Kk[8]};
    for (int k = 0; k < 9; ++k) cb->intrc[tid][k] = bf16r(S[k]);
    float Si[9];
    inv3x3(S, Si);
    for (int k = 0; k < 9; ++k) cb->Kinvc[tid][k] = bf16r(Si[k]);
  }
  __syncthreads();
  if (tid < 12) {
    int t = tid / 6, jj = tid % 6;
    int vj = jj >> 1, bj = jj & 1;
    int o = (vj + t + 1) % 3;
    float P[16];
    mm4(c2 + (bj * 3 + o) * 16, Einv_s[bj * 3 + vj], P);
    for (int r = 0; r < 3; ++r) {
      for (int c = 0; c < 3; ++c) cb->poseR[t][jj][r * 3 + c] = bf16r(P[r * 4 + c]);
      cb->poseT[t][jj][r] = bf16r(P[r * 4 + 3]);
    }
  }
}

// ---------------------------------------------------------------------------
// Weight prep, register-load layout: for each (kk,ci) tile of 256 units,
// unit u = q*64 + lane, q = nt*2 + kc; content = W[oc=nt*32+(lane&31)]
// [ch = ci*32 + (kc*2+(lane>>5))*8 .. +8] as bf16.
// ---------------------------------------------------------------------------
template <int K, int CINP, int CINR>
__global__ __launch_bounds__(256)
void prep_w(const float* __restrict__ w, unsigned short* __restrict__ Wp) {
  constexpr int NCH = CINP / 32;
  constexpr int NU = K * K * NCH * 256;
  int u = blockIdx.x * 256 + threadIdx.x;
  if (u >= NU) return;
  int slot = u & 255;
  int rest = u >> 8;
  int ci = rest % NCH;
  int kk = rest / NCH;
  int ky = kk / K, kx = kk - ky * K;
  int q = slot >> 6, lu = slot & 63;
  int nt = q >> 1, kc = q & 1;
  int oc = nt * 32 + (lu & 31);
  int gi = kc * 2 + (lu >> 5);
  int chb = ci * 32 + gi * 8;
  unsigned short o[8];
#pragma unroll
  for (int e = 0; e < 8; ++e) {
    int ch = chb + e;
    float val = (ch < CINR) ? w[(((size_t)oc * CINR + ch) * K + ky) * K + kx] : 0.0f;
    o[e] = bf16c(val);
  }
  i32x4 pk;
  pk.x = (int)o[0] | ((int)o[1] << 16);
  pk.y = (int)o[2] | ((int)o[3] << 16);
  pk.z = (int)o[4] | ((int)o[5] << 16);
  pk.w = (int)o[6] | ((int)o[7] << 16);
  *(i32x4*)&Wp[(size_t)u * 8] = pk;
}

// ---------------------------------------------------------------------------
// hn pack: x (NCHW f32) + geometry -> hn_b [bv*9600+pix][96] bf16 (BN1'd)
// ---------------------------------------------------------------------------
__global__ __launch_bounds__(256)
void hn_pack(const float* __restrict__ x, const ConstBuf* __restrict__ cb,
             unsigned short* __restrict__ hn_b) {
  int id = blockIdx.x * 256 + threadIdx.x;
  if (id >= kBV * kHW) return;
  int bv = id / kHW, pix = id - bv * kHW;
  int yy = pix / kW, xx = pix - yy * kW;
  float t0 = tanhf(x[(size_t)bv * 64 * kHW + pix]);
  float depth = 255.0f * (0.5f * t0 + 0.5f);
  float dz = bf16r(depth);
  float cx = bf16r((float)xx * dz);
  float cy = bf16r((float)yy * dz);
  const float* Ki = cb->Kinv[bv];
  float p0 = bf16r(Ki[0] * cx + Ki[1] * cy + Ki[2] * dz);
  float p1 = bf16r(Ki[3] * cx + Ki[4] * cy + Ki[5] * dz);
  float p2 = bf16r(Ki[6] * cx + Ki[7] * cy + Ki[8] * dz);
  const float* R = cb->Rw[bv];
  const float* tw = cb->tw[bv];
  float q[3];
  q[0] = bf16r(bf16r(R[0] * p0 + R[1] * p1 + R[2] * p2) + tw[0]);
  q[1] = bf16r(bf16r(R[3] * p0 + R[4] * p1 + R[5] * p2) + tw[1]);
  q[2] = bf16r(bf16r(R[6] * p0 + R[7] * p1 + R[8] * p2) + tw[2]);
  unsigned short* o = &hn_b[(size_t)id * 96];
  const float* xb = x + (size_t)bv * 64 * kHW + pix;
#pragma unroll
  for (int g = 0; g < 24; ++g) {
    float vv[4];
#pragma unroll
    for (int e = 0; e < 4; ++e) {
      int ch = g * 4 + e;
      float val;
      if (ch < 3) val = q[ch] * cb->bn1_s[ch] + cb->bn1_o[ch];
      else if (ch < 67) val = xb[(size_t)(ch - 3) * kHW] * cb->bn1_s[ch] + cb->bn1_o[ch];
      else val = 0.0f;
      vv[e] = val;
    }
    i32x2 pk = {pack2(vv[0], vv[1]), pack2(vv[2], vv[3])};
    *(i32x2*)(o + g * 4) = pk;
  }
}

// ---------------------------------------------------------------------------
// MFMA implicit-GEMM conv, 32x32x16, split-K-2 + nt-split, 16x8 output tile.
// Grid = 480 blocks (8x10x6) -> 2 co-resident blocks/CU = 4 waves/SIMD.
// Block: 512 thr (8 waves) = 2 mp (row-quads) x 2 ntq (oc-halves) x 2 kk-half.
// Wave = 2m x 1nt fragments -> 4 MFMA/kk (acc = 32 VGPR; total ~90).
// A in LDS (swizzled, per ci); B direct from global (L2-resident) with
// 2-deep register ping-pong. No barriers in the kk loop.
// Shared sized for max(A-tile, 16KB split-K scratch).
// OUT: 0 = bf16 NHWC, SiLU+BN2 (conv1)
//      1 = bf16 NHWC h_b + bf16 BNf(h) into fused_b ch64..127 (conv2)
//      2 = bf16 into fusedn[...][0..63], BNf, j->i px remap (cost)
//      3 = f32  NCHW, SiLU      (convf -> d_out)
// ---------------------------------------------------------------------------
template <int CINP, int K, int OUT>
__global__ __launch_bounds__(512)
void conv_mfma(const unsigned short* __restrict__ in_b,
               const unsigned short* __restrict__ Wp,
               const float* __restrict__ bias,
               const ConstBuf* __restrict__ cb,
               float* __restrict__ outf,
               unsigned short* __restrict__ outb,
               unsigned short* __restrict__ outb2) {
  constexpr int NCH = CINP / 32;
  constexpr int KK = K * K;
  constexpr int KH0 = (KK + 1) / 2;
  constexpr int PAD = K / 2;
  constexpr int NC = 16 + K - 1;
  constexpr int NR = 8 + K - 1;
  constexpr int NPX = NC * NR;
  // scratch for split-K reduction needs 4*64*16 floats = 8192 shorts (16KB)
  constexpr int SAW = (NPX * 32 > 8192) ? NPX * 32 : 8192;
  __shared__ unsigned short sA[SAW];

  const int tid = threadIdx.x;
  const int w = tid >> 6, l = tid & 63;
  const int mp = w & 1, ntq = (w >> 1) & 1, half = w >> 2;
  const int bx = blockIdx.x, by = blockIdx.y, bz = blockIdx.z;
  const size_t inbase = (size_t)bz * kHW;

  const int r = l & 31, h = l >> 5;           // M-row in m-tile, k-half
  const int xloc = r & 15, rhi = r >> 4;
  const int kk0 = half ? KH0 : 0;
  const int myKK = half ? (KK - KH0) : KH0;
  f32x16 acc[2] = {};                         // [m]

  for (int ci = 0; ci < NCH; ++ci) {
    __syncthreads();   // all waves done reading previous A chunk
    for (int g2 = tid; g2 < NPX * 4; g2 += 512) {
      int px = g2 >> 2, gi = g2 & 3;
      int hy = px / NC, hx = px - hy * NC;
      int gy = by * 8 - PAD + hy, gx = bx * 16 - PAD + hx;
      bool ok = ((unsigned)gy < (unsigned)kH) && ((unsigned)gx < (unsigned)kW);
      i32x4 v = {0, 0, 0, 0};
      if (ok) v = *(const i32x4*)&in_b[(inbase + gy * kW + gx) * CINP + ci * 32 + gi * 8];
      *(i32x4*)&sA[px * 32 + ((gi ^ ((px >> 2) & 3)) << 3)] = v;
    }
    __syncthreads();

    const unsigned short* wb = Wp + ((size_t)ci * 256 + (size_t)kk0 * NCH * 256) * 8;
    const size_t kstep = (size_t)NCH * 256 * 8;   // shorts per kk step
#define LOADB(dst, rdidx)                                                       \
    {                                                                           \
      const unsigned short* bp =                                                \
          wb + (size_t)(rdidx) * kstep + (size_t)(ntq * 128 + l) * 8;           \
      dst[0] = *(const bf16x8*)(bp);                                            \
      dst[1] = *(const bf16x8*)(bp + 64 * 8);                                   \
    }
#define COMPUTE(rdidx, bb)                                                      \
    {                                                                           \
      const int kk = kk0 + (rdidx);                                             \
      const int ky = kk / K, kx = kk - ky * K;                                  \
      bf16x8 a[2][2];                                                           \
      _Pragma("unroll")                                                         \
      for (int m = 0; m < 2; ++m) {                                             \
        const int hp = (4 * mp + 2 * m + rhi + ky) * NC + (xloc + kx);          \
        _Pragma("unroll")                                                       \
        for (int kc = 0; kc < 2; ++kc) {                                        \
          int gi = kc * 2 + h;                                                  \
          a[m][kc] = *(const bf16x8*)&sA[hp * 32 + ((gi ^ ((hp >> 2) & 3)) << 3)]; \
        }                                                                       \
      }                                                                         \
      _Pragma("unroll")                                                         \
      for (int m = 0; m < 2; ++m) {                                             \
        acc[m] = __builtin_amdgcn_mfma_f32_32x32x16_bf16(a[m][0], bb[0], acc[m], 0, 0, 0); \
        acc[m] = __builtin_amdgcn_mfma_f32_32x32x16_bf16(a[m][1], bb[1], acc[m], 0, 0, 0); \
      }                                                                         \
    }

    bf16x8 b0[2], b1[2];
    LOADB(b0, 0);
    int rd = 0;
    for (; rd + 2 <= myKK; rd += 2) {
      LOADB(b1, rd + 1);
      COMPUTE(rd, b0);
      if (rd + 2 < myKK) LOADB(b0, rd + 2);
      COMPUTE(rd + 1, b1);
    }
    if (rd < myKK) COMPUTE(rd, b0);
#undef LOADB
#undef COMPUTE
  }

  // ---- split-K reduction: half1 -> half0 via sA scratch (16KB region) ----
  float* scratch = (float*)sA;
#pragma unroll
  for (int cm = 0; cm < 2; ++cm) {
    float* sp = scratch + (((w & 3) * 64 + l) * 16);
    __syncthreads();
    if (half == 1) {
#pragma unroll
      for (int q = 0; q < 16; ++q) sp[q] = acc[cm][q];
    }
    __syncthreads();
    if (half == 0) {
#pragma unroll
      for (int q = 0; q < 16; ++q) acc[cm][q] += sp[q];
    }
  }
  if (half == 1) return;

  // ---- epilogue (half0): C/D col=lane&31, row=(reg&3)+8*(reg>>2)+4*(lane>>5)
#pragma unroll
  for (int m = 0; m < 2; ++m) {
    const int oc = ntq * 32 + (l & 31);
    const float bs = bias[oc];
    float s2 = 0.f, o2 = 0.f;
    if (OUT == 0) { s2 = cb->bn2_s[oc]; o2 = cb->bn2_o[oc]; }
    if (OUT == 1) { s2 = cb->bnf_s[64 + oc]; o2 = cb->bnf_o[64 + oc]; }
    if (OUT == 2) { s2 = cb->bnf_s[oc]; o2 = cb->bnf_o[oc]; }
#pragma unroll
    for (int reg = 0; reg < 16; ++reg) {
      int row = (reg & 3) + 8 * (reg >> 2) + 4 * h;
      int x = bx * 16 + (row & 15);
      if (x >= kW) continue;
      int y = by * 8 + 4 * mp + 2 * m + (row >> 4);
      float v = acc[m][reg] + bs;
      if (OUT != 2) v = v / (1.0f + expf(-v));   // SiLU
      if (OUT == 0) {
        size_t px = inbase + y * kW + x;
        outb[px * 64 + oc] = bf16c(v * s2 + o2);
      } else if (OUT == 1) {
        size_t px = inbase + y * kW + x;
        outb[px * 64 + oc] = bf16c(v);                       // h_b
        outb2[px * 128 + 64 + oc] = bf16c(v * s2 + o2);      // fused ch64..127
      } else if (OUT == 2) {
        int i = (bz & 1) * 3 + (bz >> 1);
        size_t px = (size_t)i * kHW + y * kW + x;
        outb[px * 128 + oc] = bf16c(v * s2 + o2);
      } else {
        outf[((size_t)bz * 64 + oc) * kHW + y * kW + x] = v;
      }
    }
  }
}

// ---------------------------------------------------------------------------
// Plane-sweep correlation on bf16 h (NHWC pairs). 2 pixels per wave:
// lane = (pixel-half ph, channel-pair cl). Each 4B gather serves 2 channels.
// Geometry (bit-identical chain) computed once per (pixel,d,t) by 80 jobs.
// Also emits cin ch20..83 (= f01 words) and zero ch84..95 (pack_cin fused).
// ---------------------------------------------------------------------------
__global__ __launch_bounds__(256)
void corr_kernel(const unsigned short* __restrict__ h_b, const ConstBuf* __restrict__ cb,
                 unsigned short* __restrict__ cin_b) {
  __shared__ float sgeo[4][2][40][8];
  const int tid = threadIdx.x;
  const int w = tid >> 6, lane = tid & 63;
  const int pair = blockIdx.x * 4 + w;
  const int j = pair / (kHW / 2);
  const int pix = (pair - j * (kHW / 2)) * 2;
  const int b = j & 1, v = j >> 1;
  const int ph = lane >> 5, cl = lane & 31;
  const int pixl = pix + ph;
  const int dst = b * 3 + v;
  const unsigned f01pk =
      ((const unsigned*)(h_b + ((size_t)dst * kHW + pixl) * 64))[cl];
  const float f01lo = bl(f01pk), f01hi = bh(f01pk);
  const char* sb0 = (const char*)(h_b + (size_t)(b * 3 + ((v + 1) % 3)) * kHW * 64);
  const char* sb1 = (const char*)(h_b + (size_t)(b * 3 + ((v + 2) % 3)) * kHW * 64);

  for (int job = lane; job < 80; job += 64) {
    const int p = job / 40, jj = job - p * 40;
    const int d = jj >> 1, t = jj & 1;
    const int pp = pix + p;
    const int yyp = pp / kW, xxp = pp - yyp * kW;
    const float* Kc = cb->Kinvc[j];
    const float* IC = cb->intrc[j];
    const float uf = (float)xxp, vf = (float)yyp;
    float p1_0 = bf16r(Kc[0] * uf + Kc[1] * vf + Kc[2]);
    float p1_1 = bf16r(Kc[3] * uf + Kc[4] * vf + Kc[5]);
    float p1_2 = bf16r(Kc[6] * uf + Kc[7] * vf + Kc[8]);
    const float* PR = cb->poseR[t][j];
    const float* PT = cb->poseT[t][j];
    float p20 = bf16r(PR[0] * p1_0 + PR[1] * p1_1 + PR[2] * p1_2);
    float p21 = bf16r(PR[3] * p1_0 + PR[4] * p1_1 + PR[5] * p1_2);
    float p22 = bf16r(PR[6] * p1_0 + PR[7] * p1_1 + PR[8] * p1_2);
    float dv = cb->dvals[d];
    float q0 = bf16r(bf16r(p20 * dv) + PT[0]);
    float q1 = bf16r(bf16r(p21 * dv) + PT[1]);
    float q2 = bf16r(bf16r(p22 * dv) + PT[2]);
    float s0 = bf16r(IC[0] * q0 + IC[1] * q1 + IC[2] * q2);
    float s1 = bf16r(IC[3] * q0 + IC[4] * q1 + IC[5] * q2);
    float s2 = bf16r(IC[6] * q0 + IC[7] * q1 + IC[8] * q2);
    float den = fmaxf(s2, 1e-3f);
    float g0 = 2.0f * s0 / den / 119.0f - 1.0f;
    float g1 = 2.0f * s1 / den / 79.0f - 1.0f;
    float gx = (g0 + 1.0f) * 0.5f * 119.0f;
    float gy = (g1 + 1.0f) * 0.5f * 79.0f;
    float x0f = floorf(gx), y0f = floorf(gy);
    float wx = gx - x0f, wy = gy - y0f;
    float x1f = x0f + 1.0f, y1f = y0f + 1.0f;
    float vx0 = (x0f >= 0.0f && x0f < 120.0f) ? 1.0f : 0.0f;
    float vx1 = (x1f >= 0.0f && x1f < 120.0f) ? 1.0f : 0.0f;
    float vy0 = (y0f >= 0.0f && y0f < 80.0f) ? 1.0f : 0.0f;
    float vy1 = (y1f >= 0.0f && y1f < 80.0f) ? 1.0f : 0.0f;
    int xi0 = (int)fminf(fmaxf(x0f, 0.0f), 119.0f);
    int xi1 = (int)fminf(fmaxf(x1f, 0.0f), 119.0f);
    int yi0 = (int)fminf(fmaxf(y0f, 0.0f), 79.0f);
    int yi1 = (int)fminf(fmaxf(y1f, 0.0f), 79.0f);
    // pre-combined byte offsets: (yi*kW + xi) * 64ch * 2B
    int r0b = yi0 * (kW * 128), r1b = yi1 * (kW * 128);
    int c0b = xi0 * 128, c1b = xi1 * 128;
    float* gp = sgeo[w][p][jj];
    gp[0] = __int_as_float(r0b + c0b);
    gp[1] = __int_as_float(r0b + c1b);
    gp[2] = __int_as_float(r1b + c0b);
    gp[3] = __int_as_float(r1b + c1b);
    gp[4] = ((1.0f - wx) * (1.0f - wy)) * (vx0 * vy0);
    gp[5] = (wx * (1.0f - wy)) * (vx1 * vy0);
    gp[6] = ((1.0f - wx) * wy) * (vx0 * vy1);
    gp[7] = (wx * wy) * (vx1 * vy1);
  }
  __syncthreads();

  unsigned short* op = &cin_b[(size_t)(j * kHW + pixl) * 96];
  // fused pack_cin: ch20..83 = f01 words; ch84..95 = 0
  *(unsigned*)(op + 20 + 2 * cl) = f01pk;
  if (cl < 6) *(unsigned*)(op + 84 + 2 * cl) = 0u;

  const unsigned cl4 = (unsigned)cl * 4u;
#pragma unroll 2
  for (int d = 0; d < kD; ++d) {
    float a = 0.0f;
#pragma unroll
    for (int t = 0; t < 2; ++t) {
      const char* sb = t ? sb1 : sb0;
      const float* gp = sgeo[w][ph][d * 2 + t];
      float4v ga = *(const float4v*)gp;
      float4v gb = *(const float4v*)(gp + 4);
      unsigned k00 = *(const unsigned*)(sb + ((unsigned)__float_as_int(ga.x) + cl4));
      unsigned k10 = *(const unsigned*)(sb + ((unsigned)__float_as_int(ga.y) + cl4));
      unsigned k01 = *(const unsigned*)(sb + ((unsigned)__float_as_int(ga.z) + cl4));
      unsigned k11 = *(const unsigned*)(sb + ((unsigned)__float_as_int(ga.w) + cl4));
      float al = gb.x * bl(k00) + gb.y * bl(k10) + gb.z * bl(k01) + gb.w * bl(k11);
      float ah = gb.x * bh(k00) + gb.y * bh(k10) + gb.z * bh(k01) + gb.w * bh(k11);
      a += al * f01lo + ah * f01hi;
    }
#pragma unroll
    for (int off = 16; off > 0; off >>= 1) a += __shfl_xor(a, off, 64);
    if (cl == 0) op[d] = bf16c(a * 0.0625f);   // /sqrt(64)/(V-1)
  }
}

// ---------------------------------------------------------------------------
// Launch
// ---------------------------------------------------------------------------
extern "C" void kernel_launch(void* const* d_in, const int* in_sizes, int n_in,
                              void* d_out, int out_size, void* d_ws, size_t ws_size,
                              hipStream_t stream) {
  (void)in_sizes; (void)n_in; (void)out_size; (void)ws_size;
  const float* x    = (const float*)d_in[0];
  const float* intr = (const float*)d_in[1];
  const float* c2w  = (const float*)d_in[2];
  const float* bn1g = (const float*)d_in[3];
  const float* bn1b = (const float*)d_in[4];
  const float* bn1m = (const float*)d_in[5];
  const float* bn1v = (const float*)d_in[6];
  const float* w1   = (const float*)d_in[7];
  const float* b1   = (const float*)d_in[8];
  const float* bn2g = (const float*)d_in[9];
  const float* bn2b = (const float*)d_in[10];
  const float* bn2m = (const float*)d_in[11];
  const float* bn2v = (const float*)d_in[12];
  const float* w2   = (const float*)d_in[13];
  const float* b2   = (const float*)d_in[14];
  const float* cpw  = (const float*)d_in[15];
  const float* cpb  = (const float*)d_in[16];
  const float* bnfg = (const float*)d_in[17];
  const float* bnfb = (const float*)d_in[18];
  const float* bnfm = (const float*)d_in[19];
  const float* bnfv = (const float*)d_in[20];
  const float* wf   = (const float*)d_in[21];
  const float* bff  = (const float*)d_in[22];

  char* ws = (char*)d_ws;
  ConstBuf* cb            = (ConstBuf*)ws;
  unsigned short* hn_b    = (unsigned short*)(ws + 8192);        // 6*9600*96*2
  unsigned short* h1_b    = (unsigned short*)(ws + 11067392);    // 6*9600*64*2
  unsigned short* h_b     = (unsigned short*)(ws + 18440192);    // 6*9600*64*2
  unsigned short* cin_b   = (unsigned short*)(ws + 33185792);    // 6*9600*96*2
  unsigned short* fused_b = (unsigned short*)(ws + 44244992);    // 6*9600*128*2
  unsigned short* Wp1     = (unsigned short*)(ws + 58990592);    // 995328 B
  unsigned short* Wp2     = (unsigned short*)(ws + 59985920);    // 663552 B
  unsigned short* Wpc     = (unsigned short*)(ws + 60649472);    // 110592 B
  unsigned short* Wpf     = (unsigned short*)(ws + 60760064);    // 1327104 B

  consts_kernel<<<1, 64, 0, stream>>>(intr, c2w, bn1g, bn1b, bn1m, bn1v,
                                      bn2g, bn2b, bn2m, bn2v, bnfg, bnfb, bnfm, bnfv, cb);
  prep_w<9, 96, 67><<<243, 256, 0, stream>>>(w1, Wp1);
  prep_w<9, 64, 64><<<162, 256, 0, stream>>>(w2, Wp2);
  prep_w<3, 96, 84><<<27, 256, 0, stream>>>(cpw, Wpc);
  prep_w<9, 128, 128><<<324, 256, 0, stream>>>(wf, Wpf);
  hn_pack<<<225, 256, 0, stream>>>(x, cb, hn_b);

  dim3 cgrid(8, 10, 6);
  conv_mfma<96, 9, 0><<<cgrid, 512, 0, stream>>>(hn_b, Wp1, b1, cb, nullptr, h1_b, nullptr);
  conv_mfma<64, 9, 1><<<cgrid, 512, 0, stream>>>(h1_b, Wp2, b2, cb, nullptr, h_b, fused_b);
  corr_kernel<<<7200, 256, 0, stream>>>(h_b, cb, cin_b);
  conv_mfma<96, 3, 2><<<cgrid, 512, 0, stream>>>(cin_b, Wpc, cpb, cb, nullptr, fused_b, nullptr);
  conv_mfma<128, 9, 3><<<cgrid, 512, 0, stream>>>(fused_b, Wpf, bff, cb, (float*)d_out, nullptr, nullptr);
}

// Round 21
// 332.582 us; speedup vs baseline: 1.0146x; 1.0146x over previous
//
#include <hip/hip_runtime.h>
#include <math.h>

static constexpr int kH  = 80;
static constexpr int kW  = 120;
static constexpr int kHW = kH * kW;     // 9600
static constexpr int kBV = 6;
static constexpr int kD  = 20;

typedef __attribute__((ext_vector_type(8)))  short bf16x8;
typedef __attribute__((ext_vector_type(16))) float f32x16;
typedef __attribute__((ext_vector_type(4)))  int   i32x4;
typedef __attribute__((ext_vector_type(2)))  int   i32x2;
typedef __attribute__((ext_vector_type(4)))  float float4v;

__device__ __forceinline__ float bf16r(float x) {
  unsigned u = __float_as_uint(x);
  u += 0x7FFFu + ((u >> 16) & 1u);
  return __uint_as_float(u & 0xFFFF0000u);
}
__device__ __forceinline__ unsigned short bf16c(float x) {
  unsigned u = __float_as_uint(x);
  u += 0x7FFFu + ((u >> 16) & 1u);
  return (unsigned short)(u >> 16);
}
__device__ __forceinline__ int pack2(float a, float b) {
  return (int)((unsigned)bf16c(a) | ((unsigned)bf16c(b) << 16));
}
__device__ __forceinline__ float bl(unsigned pk) {  // low bf16 of pair -> f32
  return __uint_as_float(pk << 16);
}
__device__ __forceinline__ float bh(unsigned pk) {  // high bf16 of pair -> f32
  return __uint_as_float(pk & 0xFFFF0000u);
}

struct ConstBuf {
  float bn1_s[67], bn1_o[67];
  float bn2_s[64], bn2_o[64];
  float bnf_s[128], bnf_o[128];
  float Kinv[6][9];
  float Rw[6][9];
  float tw[6][3];
  float Kinvc[6][9];
  float intrc[6][9];
  float poseR[2][6][9];
  float poseT[2][6][3];
  float dvals[20];
};

__device__ void inv3x3(const float* A, float* o) {
  float a = A[0], b = A[1], c = A[2];
  float d = A[3], e = A[4], f = A[5];
  float g = A[6], h = A[7], i = A[8];
  float det = a * (e * i - f * h) - b * (d * i - f * g) + c * (d * h - e * g);
  float id = 1.0f / det;
  o[0] = (e * i - f * h) * id;
  o[1] = -(b * i - c * h) * id;
  o[2] = (b * f - c * e) * id;
  o[3] = -(d * i - f * g) * id;
  o[4] = (a * i - c * g) * id;
  o[5] = -(a * f - c * d) * id;
  o[6] = (d * h - e * g) * id;
  o[7] = -(a * h - b * g) * id;
  o[8] = (a * e - b * d) * id;
}

__device__ void inv4x4(const float* A, float* out) {
  float M[4][8];
  for (int r = 0; r < 4; ++r) {
    for (int c = 0; c < 4; ++c) M[r][c] = A[r * 4 + c];
    for (int c = 0; c < 4; ++c) M[r][4 + c] = (r == c) ? 1.0f : 0.0f;
  }
  for (int col = 0; col < 4; ++col) {
    int p = col;
    float best = fabsf(M[col][col]);
    for (int r = col + 1; r < 4; ++r) {
      float v = fabsf(M[r][col]);
      if (v > best) { best = v; p = r; }
    }
    if (p != col)
      for (int c = 0; c < 8; ++c) { float t = M[col][c]; M[col][c] = M[p][c]; M[p][c] = t; }
    float inv = 1.0f / M[col][col];
    for (int c = 0; c < 8; ++c) M[col][c] *= inv;
    for (int r = 0; r < 4; ++r) {
      if (r == col) continue;
      float f = M[r][col];
      for (int c = 0; c < 8; ++c) M[r][c] -= f * M[col][c];
    }
  }
  for (int r = 0; r < 4; ++r)
    for (int c = 0; c < 4; ++c) out[r * 4 + c] = M[r][4 + c];
}

__device__ void mm4(const float* A, const float* B, float* C) {
  for (int r = 0; r < 4; ++r)
    for (int c = 0; c < 4; ++c) {
      float s = 0.0f;
      for (int k = 0; k < 4; ++k) s += A[r * 4 + k] * B[k * 4 + c];
      C[r * 4 + c] = s;
    }
}

// ---------------------------------------------------------------------------
// Kernel 0: constants
// ---------------------------------------------------------------------------
__global__ void consts_kernel(const float* __restrict__ intr, const float* __restrict__ c2,
                              const float* g1, const float* b1, const float* m1, const float* v1,
                              const float* g2, const float* b2, const float* m2, const float* v2,
                              const float* gf, const float* bff, const float* mf, const float* vff,
                              ConstBuf* cb) {
  int tid = threadIdx.x;
  for (int c = tid; c < 67; c += 64) {
    float s = g1[c] / sqrtf(v1[c] + 1e-5f);
    cb->bn1_s[c] = s; cb->bn1_o[c] = b1[c] - m1[c] * s;
  }
  for (int c = tid; c < 64; c += 64) {
    float s = g2[c] / sqrtf(v2[c] + 1e-5f);
    cb->bn2_s[c] = s; cb->bn2_o[c] = b2[c] - m2[c] * s;
  }
  for (int c = tid; c < 128; c += 64) {
    float s = gf[c] / sqrtf(vff[c] + 1e-5f);
    cb->bnf_s[c] = s; cb->bnf_o[c] = bff[c] - mf[c] * s;
  }
  if (tid < 20) {
    float l = (1.0f / 19.0f) * (float)tid;
    cb->dvals[tid] = bf16r(1.0f / (0.01f + l * 9.99f));
  }
  __shared__ float Einv_s[6][16];
  if (tid < 6) {
    float Ki[9];
    inv3x3(intr + tid * 9, Ki);
    for (int k = 0; k < 9; ++k) cb->Kinv[tid][k] = bf16r(Ki[k]);
    const float* T = c2 + tid * 16;
    cb->Rw[tid][0] = bf16r(T[0]);  cb->Rw[tid][1] = bf16r(T[1]);  cb->Rw[tid][2] = bf16r(T[2]);
    cb->Rw[tid][3] = bf16r(T[4]);  cb->Rw[tid][4] = bf16r(T[5]);  cb->Rw[tid][5] = bf16r(T[6]);
    cb->Rw[tid][6] = bf16r(T[8]);  cb->Rw[tid][7] = bf16r(T[9]);  cb->Rw[tid][8] = bf16r(T[10]);
    cb->tw[tid][0] = bf16r(T[3]);  cb->tw[tid][1] = bf16r(T[7]);  cb->tw[tid][2] = bf16r(T[11]);
    inv4x4(T, Einv_s[tid]);
    int vj = tid >> 1, bj = tid & 1, ii = bj * 3 + vj;
    const float* Kk = intr + ii * 9;
    float S[9] = {Kk[0] * 120.0f, Kk[1] * 120.0f, Kk[2] * 120.0f,
                  Kk[3] * 80.0f,  Kk[4] * 80.0f,  Kk[5] * 80.0f,
                  Kk[6],          Kk[7],          Kk[8]};
    for (int k = 0; k < 9; ++k) cb->intrc[tid][k] = bf16r(S[k]);
    float Si[9];
    inv3x3(S, Si);
    for (int k = 0; k < 9; ++k) cb->Kinvc[tid][k] = bf16r(Si[k]);
  }
  __syncthreads();
  if (tid < 12) {
    int t = tid / 6, jj = tid % 6;
    int vj = jj >> 1, bj = jj & 1;
    int o = (vj + t + 1) % 3;
    float P[16];
    mm4(c2 + (bj * 3 + o) * 16, Einv_s[bj * 3 + vj], P);
    for (int r = 0; r < 3; ++r) {
      for (int c = 0; c < 3; ++c) cb->poseR[t][jj][r * 3 + c] = bf16r(P[r * 4 + c]);
      cb->poseT[t][jj][r] = bf16r(P[r * 4 + 3]);
    }
  }
}

// ---------------------------------------------------------------------------
// Weight prep, register-load layout: for each (kk,ci) tile of 256 units,
// unit u = q*64 + lane, q = nt*2 + kc; content = W[oc=nt*32+(lane&31)]
// [ch = ci*32 + (kc*2+(lane>>5))*8 .. +8] as bf16.
// ---------------------------------------------------------------------------
template <int K, int CINP, int CINR>
__global__ __launch_bounds__(256)
void prep_w(const float* __restrict__ w, unsigned short* __restrict__ Wp) {
  constexpr int NCH = CINP / 32;
  constexpr int NU = K * K * NCH * 256;
  int u = blockIdx.x * 256 + threadIdx.x;
  if (u >= NU) return;
  int slot = u & 255;
  int rest = u >> 8;
  int ci = rest % NCH;
  int kk = rest / NCH;
  int ky = kk / K, kx = kk - ky * K;
  int q = slot >> 6, lu = slot & 63;
  int nt = q >> 1, kc = q & 1;
  int oc = nt * 32 + (lu & 31);
  int gi = kc * 2 + (lu >> 5);
  int chb = ci * 32 + gi * 8;
  unsigned short o[8];
#pragma unroll
  for (int e = 0; e < 8; ++e) {
    int ch = chb + e;
    float val = (ch < CINR) ? w[(((size_t)oc * CINR + ch) * K + ky) * K + kx] : 0.0f;
    o[e] = bf16c(val);
  }
  i32x4 pk;
  pk.x = (int)o[0] | ((int)o[1] << 16);
  pk.y = (int)o[2] | ((int)o[3] << 16);
  pk.z = (int)o[4] | ((int)o[5] << 16);
  pk.w = (int)o[6] | ((int)o[7] << 16);
  *(i32x4*)&Wp[(size_t)u * 8] = pk;
}

// ---------------------------------------------------------------------------
// hn pack: x (NCHW f32) + geometry -> hn_b [bv*9600+pix][96] bf16 (BN1'd)
// ---------------------------------------------------------------------------
__global__ __launch_bounds__(256)
void hn_pack(const float* __restrict__ x, const ConstBuf* __restrict__ cb,
             unsigned short* __restrict__ hn_b) {
  int id = blockIdx.x * 256 + threadIdx.x;
  if (id >= kBV * kHW) return;
  int bv = id / kHW, pix = id - bv * kHW;
  int yy = pix / kW, xx = pix - yy * kW;
  float t0 = tanhf(x[(size_t)bv * 64 * kHW + pix]);
  float depth = 255.0f * (0.5f * t0 + 0.5f);
  float dz = bf16r(depth);
  float cx = bf16r((float)xx * dz);
  float cy = bf16r((float)yy * dz);
  const float* Ki = cb->Kinv[bv];
  float p0 = bf16r(Ki[0] * cx + Ki[1] * cy + Ki[2] * dz);
  float p1 = bf16r(Ki[3] * cx + Ki[4] * cy + Ki[5] * dz);
  float p2 = bf16r(Ki[6] * cx + Ki[7] * cy + Ki[8] * dz);
  const float* R = cb->Rw[bv];
  const float* tw = cb->tw[bv];
  float q[3];
  q[0] = bf16r(bf16r(R[0] * p0 + R[1] * p1 + R[2] * p2) + tw[0]);
  q[1] = bf16r(bf16r(R[3] * p0 + R[4] * p1 + R[5] * p2) + tw[1]);
  q[2] = bf16r(bf16r(R[6] * p0 + R[7] * p1 + R[8] * p2) + tw[2]);
  unsigned short* o = &hn_b[(size_t)id * 96];
  const float* xb = x + (size_t)bv * 64 * kHW + pix;
#pragma unroll
  for (int g = 0; g < 24; ++g) {
    float vv[4];
#pragma unroll
    for (int e = 0; e < 4; ++e) {
      int ch = g * 4 + e;
      float val;
      if (ch < 3) val = q[ch] * cb->bn1_s[ch] + cb->bn1_o[ch];
      else if (ch < 67) val = xb[(size_t)(ch - 3) * kHW] * cb->bn1_s[ch] + cb->bn1_o[ch];
      else val = 0.0f;
      vv[e] = val;
    }
    i32x2 pk = {pack2(vv[0], vv[1]), pack2(vv[2], vv[3])};
    *(i32x2*)(o + g * 4) = pk;
  }
}

// ---------------------------------------------------------------------------
// MFMA implicit-GEMM conv, 32x32x16, split-K-2 + nt-split, 16x8 output tile.
// Grid = 480 blocks (8x10x6) -> 2 co-resident blocks/CU = 4 waves/SIMD.
// Block: 512 thr (8 waves) = 2 mp (row-quads) x 2 ntq (oc-halves) x 2 kk-half.
// Wave = 2m x 1nt fragments -> 4 MFMA/kk. A in LDS (swizzled, per ci);
// B direct from global (L2-resident) with 2-deep register ping-pong and a
// RUNNING pointer (no per-kk index multiply). ky/kx tracked incrementally
// (no per-kk integer division). Split-K scratch PADDED to 17-float stride
// (conflict-free). No barriers in the kk loop.
// OUT: 0 = bf16 NHWC, SiLU+BN2 (conv1)
//      1 = bf16 NHWC h_b + bf16 BNf(h) into fused_b ch64..127 (conv2)
//      2 = bf16 into fusedn[...][0..63], BNf, j->i px remap (cost)
//      3 = f32  NCHW, SiLU      (convf -> d_out)
// ---------------------------------------------------------------------------
template <int CINP, int K, int OUT>
__global__ __launch_bounds__(512)
void conv_mfma(const unsigned short* __restrict__ in_b,
               const unsigned short* __restrict__ Wp,
               const float* __restrict__ bias,
               const ConstBuf* __restrict__ cb,
               float* __restrict__ outf,
               unsigned short* __restrict__ outb,
               unsigned short* __restrict__ outb2) {
  constexpr int NCH = CINP / 32;
  constexpr int KK = K * K;
  constexpr int KH0 = (KK + 1) / 2;
  constexpr int PAD = K / 2;
  constexpr int NC = 16 + K - 1;
  constexpr int NR = 8 + K - 1;
  constexpr int NPX = NC * NR;
  // split-K scratch: 4 groups x 64 lanes x 17 floats (padded) = 17408 B
  constexpr int SAW = (NPX * 32 > 8704) ? NPX * 32 : 8704;
  __shared__ unsigned short sA[SAW];

  const int tid = threadIdx.x;
  const int w = tid >> 6, l = tid & 63;
  const int mp = w & 1, ntq = (w >> 1) & 1, half = w >> 2;
  const int bx = blockIdx.x, by = blockIdx.y, bz = blockIdx.z;
  const size_t inbase = (size_t)bz * kHW;

  const int r = l & 31, h = l >> 5;           // M-row in m-tile, k-half
  const int xloc = r & 15, rhi = r >> 4;
  const int kk0 = half ? KH0 : 0;
  const int myKK = half ? (KK - KH0) : KH0;
  const int ky00 = kk0 / K, kx00 = kk0 - ky00 * K;   // computed once
  f32x16 acc[2] = {};                         // [m]

  for (int ci = 0; ci < NCH; ++ci) {
    __syncthreads();   // all waves done reading previous A chunk
    for (int g2 = tid; g2 < NPX * 4; g2 += 512) {
      int px = g2 >> 2, gi = g2 & 3;
      int hy = px / NC, hx = px - hy * NC;
      int gy = by * 8 - PAD + hy, gx = bx * 16 - PAD + hx;
      bool ok = ((unsigned)gy < (unsigned)kH) && ((unsigned)gx < (unsigned)kW);
      i32x4 v = {0, 0, 0, 0};
      if (ok) v = *(const i32x4*)&in_b[(inbase + gy * kW + gx) * CINP + ci * 32 + gi * 8];
      *(i32x4*)&sA[px * 32 + ((gi ^ ((px >> 2) & 3)) << 3)] = v;
    }
    __syncthreads();

    const size_t kstep = (size_t)NCH * 256 * 8;   // shorts per kk step
    const unsigned short* bp_run =
        Wp + ((size_t)ci * 256 + (size_t)kk0 * NCH * 256) * 8 + (size_t)(ntq * 128 + l) * 8;
    int ky = ky00, kx = kx00;
#define LOADB(dst)                                                              \
    {                                                                           \
      dst[0] = *(const bf16x8*)(bp_run);                                        \
      dst[1] = *(const bf16x8*)(bp_run + 64 * 8);                               \
      bp_run += kstep;                                                          \
    }
#define COMPUTE(bb)                                                             \
    {                                                                           \
      bf16x8 a[2][2];                                                           \
      _Pragma("unroll")                                                         \
      for (int m = 0; m < 2; ++m) {                                             \
        const int hp = (4 * mp + 2 * m + rhi + ky) * NC + (xloc + kx);          \
        _Pragma("unroll")                                                       \
        for (int kc = 0; kc < 2; ++kc) {                                        \
          int gi = kc * 2 + h;                                                  \
          a[m][kc] = *(const bf16x8*)&sA[hp * 32 + ((gi ^ ((hp >> 2) & 3)) << 3)]; \
        }                                                                       \
      }                                                                         \
      _Pragma("unroll")                                                         \
      for (int m = 0; m < 2; ++m) {                                             \
        acc[m] = __builtin_amdgcn_mfma_f32_32x32x16_bf16(a[m][0], bb[0], acc[m], 0, 0, 0); \
        acc[m] = __builtin_amdgcn_mfma_f32_32x32x16_bf16(a[m][1], bb[1], acc[m], 0, 0, 0); \
      }                                                                         \
      if (++kx == K) { kx = 0; ++ky; }                                          \
    }

    bf16x8 b0[2], b1[2];
    LOADB(b0);
    int rd = 0;
    for (; rd + 2 <= myKK; rd += 2) {
      LOADB(b1);
      COMPUTE(b0);
      if (rd + 2 < myKK) LOADB(b0);
      COMPUTE(b1);
    }
    if (rd < myKK) COMPUTE(b0);
#undef LOADB
#undef COMPUTE
  }

  // ---- split-K reduction: half1 -> half0 via padded sA scratch ----
  float* scratch = (float*)sA;
#pragma unroll
  for (int cm = 0; cm < 2; ++cm) {
    float* sp = scratch + (((w & 3) * 64 + l) * 17);
    __syncthreads();
    if (half == 1) {
#pragma unroll
      for (int q = 0; q < 16; ++q) sp[q] = acc[cm][q];
    }
    __syncthreads();
    if (half == 0) {
#pragma unroll
      for (int q = 0; q < 16; ++q) acc[cm][q] += sp[q];
    }
  }
  if (half == 1) return;

  // ---- epilogue (half0): C/D col=lane&31, row=(reg&3)+8*(reg>>2)+4*(lane>>5)
#pragma unroll
  for (int m = 0; m < 2; ++m) {
    const int oc = ntq * 32 + (l & 31);
    const float bs = bias[oc];
    float s2 = 0.f, o2 = 0.f;
    if (OUT == 0) { s2 = cb->bn2_s[oc]; o2 = cb->bn2_o[oc]; }
    if (OUT == 1) { s2 = cb->bnf_s[64 + oc]; o2 = cb->bnf_o[64 + oc]; }
    if (OUT == 2) { s2 = cb->bnf_s[oc]; o2 = cb->bnf_o[oc]; }
#pragma unroll
    for (int reg = 0; reg < 16; ++reg) {
      int row = (reg & 3) + 8 * (reg >> 2) + 4 * h;
      int x = bx * 16 + (row & 15);
      if (x >= kW) continue;
      int y = by * 8 + 4 * mp + 2 * m + (row >> 4);
      float v = acc[m][reg] + bs;
      if (OUT != 2) v = v / (1.0f + expf(-v));   // SiLU
      if (OUT == 0) {
        size_t px = inbase + y * kW + x;
        outb[px * 64 + oc] = bf16c(v * s2 + o2);
      } else if (OUT == 1) {
        size_t px = inbase + y * kW + x;
        outb[px * 64 + oc] = bf16c(v);                       // h_b
        outb2[px * 128 + 64 + oc] = bf16c(v * s2 + o2);      // fused ch64..127
      } else if (OUT == 2) {
        int i = (bz & 1) * 3 + (bz >> 1);
        size_t px = (size_t)i * kHW + y * kW + x;
        outb[px * 128 + oc] = bf16c(v * s2 + o2);
      } else {
        outf[((size_t)bz * 64 + oc) * kHW + y * kW + x] = v;
      }
    }
  }
}

// ---------------------------------------------------------------------------
// Plane-sweep correlation on bf16 h (NHWC pairs). 2 pixels per wave:
// lane = (pixel-half ph, channel-pair cl). Each 4B gather serves 2 channels.
// Geometry (bit-identical chain) computed once per (pixel,d,t) by 80 jobs.
// Also emits cin ch20..83 (= f01 words) and zero ch84..95 (pack_cin fused).
// ---------------------------------------------------------------------------
__global__ __launch_bounds__(256)
void corr_kernel(const unsigned short* __restrict__ h_b, const ConstBuf* __restrict__ cb,
                 unsigned short* __restrict__ cin_b) {
  __shared__ float sgeo[4][2][40][8];
  const int tid = threadIdx.x;
  const int w = tid >> 6, lane = tid & 63;
  const int pair = blockIdx.x * 4 + w;
  const int j = pair / (kHW / 2);
  const int pix = (pair - j * (kHW / 2)) * 2;
  const int b = j & 1, v = j >> 1;
  const int ph = lane >> 5, cl = lane & 31;
  const int pixl = pix + ph;
  const int dst = b * 3 + v;
  const unsigned f01pk =
      ((const unsigned*)(h_b + ((size_t)dst * kHW + pixl) * 64))[cl];
  const float f01lo = bl(f01pk), f01hi = bh(f01pk);
  const char* sb0 = (const char*)(h_b + (size_t)(b * 3 + ((v + 1) % 3)) * kHW * 64);
  const char* sb1 = (const char*)(h_b + (size_t)(b * 3 + ((v + 2) % 3)) * kHW * 64);

  for (int job = lane; job < 80; job += 64) {
    const int p = job / 40, jj = job - p * 40;
    const int d = jj >> 1, t = jj & 1;
    const int pp = pix + p;
    const int yyp = pp / kW, xxp = pp - yyp * kW;
    const float* Kc = cb->Kinvc[j];
    const float* IC = cb->intrc[j];
    const float uf = (float)xxp, vf = (float)yyp;
    float p1_0 = bf16r(Kc[0] * uf + Kc[1] * vf + Kc[2]);
    float p1_1 = bf16r(Kc[3] * uf + Kc[4] * vf + Kc[5]);
    float p1_2 = bf16r(Kc[6] * uf + Kc[7] * vf + Kc[8]);
    const float* PR = cb->poseR[t][j];
    const float* PT = cb->poseT[t][j];
    float p20 = bf16r(PR[0] * p1_0 + PR[1] * p1_1 + PR[2] * p1_2);
    float p21 = bf16r(PR[3] * p1_0 + PR[4] * p1_1 + PR[5] * p1_2);
    float p22 = bf16r(PR[6] * p1_0 + PR[7] * p1_1 + PR[8] * p1_2);
    float dv = cb->dvals[d];
    float q0 = bf16r(bf16r(p20 * dv) + PT[0]);
    float q1 = bf16r(bf16r(p21 * dv) + PT[1]);
    float q2 = bf16r(bf16r(p22 * dv) + PT[2]);
    float s0 = bf16r(IC[0] * q0 + IC[1] * q1 + IC[2] * q2);
    float s1 = bf16r(IC[3] * q0 + IC[4] * q1 + IC[5] * q2);
    float s2 = bf16r(IC[6] * q0 + IC[7] * q1 + IC[8] * q2);
    float den = fmaxf(s2, 1e-3f);
    float g0 = 2.0f * s0 / den / 119.0f - 1.0f;
    float g1 = 2.0f * s1 / den / 79.0f - 1.0f;
    float gx = (g0 + 1.0f) * 0.5f * 119.0f;
    float gy = (g1 + 1.0f) * 0.5f * 79.0f;
    float x0f = floorf(gx), y0f = floorf(gy);
    float wx = gx - x0f, wy = gy - y0f;
    float x1f = x0f + 1.0f, y1f = y0f + 1.0f;
    float vx0 = (x0f >= 0.0f && x0f < 120.0f) ? 1.0f : 0.0f;
    float vx1 = (x1f >= 0.0f && x1f < 120.0f) ? 1.0f : 0.0f;
    float vy0 = (y0f >= 0.0f && y0f < 80.0f) ? 1.0f : 0.0f;
    float vy1 = (y1f >= 0.0f && y1f < 80.0f) ? 1.0f : 0.0f;
    int xi0 = (int)fminf(fmaxf(x0f, 0.0f), 119.0f);
    int xi1 = (int)fminf(fmaxf(x1f, 0.0f), 119.0f);
    int yi0 = (int)fminf(fmaxf(y0f, 0.0f), 79.0f);
    int yi1 = (int)fminf(fmaxf(y1f, 0.0f), 79.0f);
    // pre-combined byte offsets: (yi*kW + xi) * 64ch * 2B
    int r0b = yi0 * (kW * 128), r1b = yi1 * (kW * 128);
    int c0b = xi0 * 128, c1b = xi1 * 128;
    float* gp = sgeo[w][p][jj];
    gp[0] = __int_as_float(r0b + c0b);
    gp[1] = __int_as_float(r0b + c1b);
    gp[2] = __int_as_float(r1b + c0b);
    gp[3] = __int_as_float(r1b + c1b);
    gp[4] = ((1.0f - wx) * (1.0f - wy)) * (vx0 * vy0);
    gp[5] = (wx * (1.0f - wy)) * (vx1 * vy0);
    gp[6] = ((1.0f - wx) * wy) * (vx0 * vy1);
    gp[7] = (wx * wy) * (vx1 * vy1);
  }
  __syncthreads();

  unsigned short* op = &cin_b[(size_t)(j * kHW + pixl) * 96];
  // fused pack_cin: ch20..83 = f01 words; ch84..95 = 0
  *(unsigned*)(op + 20 + 2 * cl) = f01pk;
  if (cl < 6) *(unsigned*)(op + 84 + 2 * cl) = 0u;

  const unsigned cl4 = (unsigned)cl * 4u;
#pragma unroll 2
  for (int d = 0; d < kD; ++d) {
    float a = 0.0f;
#pragma unroll
    for (int t = 0; t < 2; ++t) {
      const char* sb = t ? sb1 : sb0;
      const float* gp = sgeo[w][ph][d * 2 + t];
      float4v ga = *(const float4v*)gp;
      float4v gb = *(const float4v*)(gp + 4);
      unsigned k00 = *(const unsigned*)(sb + ((unsigned)__float_as_int(ga.x) + cl4));
      unsigned k10 = *(const unsigned*)(sb + ((unsigned)__float_as_int(ga.y) + cl4));
      unsigned k01 = *(const unsigned*)(sb + ((unsigned)__float_as_int(ga.z) + cl4));
      unsigned k11 = *(const unsigned*)(sb + ((unsigned)__float_as_int(ga.w) + cl4));
      float al = gb.x * bl(k00) + gb.y * bl(k10) + gb.z * bl(k01) + gb.w * bl(k11);
      float ah = gb.x * bh(k00) + gb.y * bh(k10) + gb.z * bh(k01) + gb.w * bh(k11);
      a += al * f01lo + ah * f01hi;
    }
#pragma unroll
    for (int off = 16; off > 0; off >>= 1) a += __shfl_xor(a, off, 64);
    if (cl == 0) op[d] = bf16c(a * 0.0625f);   // /sqrt(64)/(V-1)
  }
}

// ---------------------------------------------------------------------------
// Launch
// ---------------------------------------------------------------------------
extern "C" void kernel_launch(void* const* d_in, const int* in_sizes, int n_in,
                              void* d_out, int out_size, void* d_ws, size_t ws_size,
                              hipStream_t stream) {
  (void)in_sizes; (void)n_in; (void)out_size; (void)ws_size;
  const float* x    = (const float*)d_in[0];
  const float* intr = (const float*)d_in[1];
  const float* c2w  = (const float*)d_in[2];
  const float* bn1g = (const float*)d_in[3];
  const float* bn1b = (const float*)d_in[4];
  const float* bn1m = (const float*)d_in[5];
  const float* bn1v = (const float*)d_in[6];
  const float* w1   = (const float*)d_in[7];
  const float* b1   = (const float*)d_in[8];
  const float* bn2g = (const float*)d_in[9];
  const float* bn2b = (const float*)d_in[10];
  const float* bn2m = (const float*)d_in[11];
  const float* bn2v = (const float*)d_in[12];
  const float* w2   = (const float*)d_in[13];
  const float* b2   = (const float*)d_in[14];
  const float* cpw  = (const float*)d_in[15];
  const float* cpb  = (const float*)d_in[16];
  const float* bnfg = (const float*)d_in[17];
  const float* bnfb = (const float*)d_in[18];
  const float* bnfm = (const float*)d_in[19];
  const float* bnfv = (const float*)d_in[20];
  const float* wf   = (const float*)d_in[21];
  const float* bff  = (const float*)d_in[22];

  char* ws = (char*)d_ws;
  ConstBuf* cb            = (ConstBuf*)ws;
  unsigned short* hn_b    = (unsigned short*)(ws + 8192);        // 6*9600*96*2
  unsigned short* h1_b    = (unsigned short*)(ws + 11067392);    // 6*9600*64*2
  unsigned short* h_b     = (unsigned short*)(ws + 18440192);    // 6*9600*64*2
  unsigned short* cin_b   = (unsigned short*)(ws + 33185792);    // 6*9600*96*2
  unsigned short* fused_b = (unsigned short*)(ws + 44244992);    // 6*9600*128*2
  unsigned short* Wp1     = (unsigned short*)(ws + 58990592);    // 995328 B
  unsigned short* Wp2     = (unsigned short*)(ws + 59985920);    // 663552 B
  unsigned short* Wpc     = (unsigned short*)(ws + 60649472);    // 110592 B
  unsigned short* Wpf     = (unsigned short*)(ws + 60760064);    // 1327104 B

  consts_kernel<<<1, 64, 0, stream>>>(intr, c2w, bn1g, bn1b, bn1m, bn1v,
                                      bn2g, bn2b, bn2m, bn2v, bnfg, bnfb, bnfm, bnfv, cb);
  prep_w<9, 96, 67><<<243, 256, 0, stream>>>(w1, Wp1);
  prep_w<9, 64, 64><<<162, 256, 0, stream>>>(w2, Wp2);
  prep_w<3, 96, 84><<<27, 256, 0, stream>>>(cpw, Wpc);
  prep_w<9, 128, 128><<<324, 256, 0, stream>>>(wf, Wpf);
  hn_pack<<<225, 256, 0, stream>>>(x, cb, hn_b);

  dim3 cgrid(8, 10, 6);
  conv_mfma<96, 9, 0><<<cgrid, 512, 0, stream>>>(hn_b, Wp1, b1, cb, nullptr, h1_b, nullptr);
  conv_mfma<64, 9, 1><<<cgrid, 512, 0, stream>>>(h1_b, Wp2, b2, cb, nullptr, h_b, fused_b);
  corr_kernel<<<7200, 256, 0, stream>>>(h_b, cb, cin_b);
  conv_mfma<96, 3, 2><<<cgrid, 512, 0, stream>>>(cin_b, Wpc, cpb, cb, nullptr, fused_b, nullptr);
  conv_mfma<128, 9, 3><<<cgrid, 512, 0, stream>>>(fused_b, Wpf, bff, cb, (float*)d_out, nullptr, nullptr);
}